// Round 4
// baseline (222.895 us; speedup 1.0000x reference)
//
#include <hip/hip_runtime.h>

// Fused: per-channel affine+relu -> dilated(2) 3x3 box-sum (zero pad) ->
// sigmoid gate -> multiply -> 2x nearest upsample -> add y.
//
// Mapping: 1 thread = 2 adjacent input pixels -> 4x2 output block; one block
// = one full input row (lane-contiguous float4 on y/out; R4).
// x taps: 3 float2 loads per row, UNCONDITIONAL with clamped addresses,
// masked arithmetically post-relu (R3). Plain cached stores (nt -> 2.5x WA).
// R5: XCD-chunked block swizzle (kept; -24 MB HBM fetch).
// R6/R7: liveness pins alone didn't move time -> regalloc-serialization
// refuted as dominant effect.
//
// R8: waves live ~17K cy (Little's law: 192 waves/CU, ~22 resident, 152K cy)
// while no pipe exceeds 40% -> throughput is capped by bytes-in-flight per
// CU (outstanding-miss slots), not by any service rate. Fix: 4 rows per
// block, explicitly 2-deep software pipeline -- stage k+1's 26 load values
// are asm-pinned live before stage k's compute, so every wave holds TWO
// full stages of memory in flight. Grid 12288 -> 3072 (4x work/wave).
// Bonus: x rows overlap across the block's 4 iterations (r2 of iter k is
// r1 of iter k+2) -> L1 hits; per-block scalar setup amortized 4x.

#define DIA 2

struct Stage {
    float2 L0, M0, R0, L1, M1, R1, L2, M2, R2;
    float4 ya, yb;
};

// Force every element of a stage live-in-register at this point: the loads
// producing them must have issued, and their 26 destination VGPRs coexist.
#define PIN(s) asm volatile("" :: \
    "v"((s).L0.x), "v"((s).L0.y), "v"((s).M0.x), "v"((s).M0.y), \
    "v"((s).R0.x), "v"((s).R0.y), "v"((s).L1.x), "v"((s).L1.y), \
    "v"((s).M1.x), "v"((s).M1.y), "v"((s).R1.x), "v"((s).R1.y), \
    "v"((s).L2.x), "v"((s).L2.y), "v"((s).M2.x), "v"((s).M2.y), \
    "v"((s).R2.x), "v"((s).R2.y), \
    "v"((s).ya.x), "v"((s).ya.y), "v"((s).ya.z), "v"((s).ya.w), \
    "v"((s).yb.x), "v"((s).yb.y), "v"((s).yb.z), "v"((s).yb.w))

__global__ __launch_bounds__(256) void fused_kernel(
    const float* __restrict__ x, const float* __restrict__ y,
    const float* __restrict__ w1v, const float* __restrict__ b1v,
    const float* __restrict__ w2v, const float* __restrict__ b2v,
    float* __restrict__ out)
{
    constexpr int C = 3, H = 512, W = 512, W2 = 1024;
    constexpr int NBLK = 3072, CHUNK = NBLK / 8;

    // XCD-aware swizzle: consecutive hardware blockIdx round-robins across
    // 8 XCDs; remap so each XCD owns a contiguous chunk (3072 % 8 == 0).
    int g = blockIdx.x;
    int p = (g & 7) * CHUNK + (g >> 3);

    int row0 = p * 4;                    // logical row id = bc*512 + h0
    int bc   = row0 >> 9;                // 0..23; rows 4p..4p+3 same image
    int h0   = row0 & (H - 1);           // multiple of 4 -> h0+3 <= 511
    int c    = bc % C;
    int w0   = threadIdx.x * 2;          // even, 0..510, lane-contiguous

    const float s_w1 = w1v[c], s_b1 = b1v[c];
    const float s_w2 = w2v[c], s_b2 = b2v[c];

    const bool lok = (w0 > 0), rok = (w0 + 2 < W);
    const float mL = lok ? 1.f : 0.f;
    const float mR = rok ? 1.f : 0.f;
    const int wl = lok ? (w0 - 2) : w0;   // clamped, always in-bounds, 8B-aligned
    const int wr = rok ? (w0 + 2) : w0;

    const float* __restrict__ ximg = x + (size_t)bc * H * W;

    auto load_stage = [&](int h) -> Stage {
        const float* r1 = ximg + (size_t)h * W;
        const float* r0 = (h >= DIA)     ? (r1 - DIA * W) : r1;
        const float* r2 = (h < H - DIA)  ? (r1 + DIA * W) : r1;
        Stage s;
        s.L0 = *(const float2*)(r0 + wl);
        s.M0 = *(const float2*)(r0 + w0);
        s.R0 = *(const float2*)(r0 + wr);
        s.L1 = *(const float2*)(r1 + wl);
        s.M1 = *(const float2*)(r1 + w0);
        s.R1 = *(const float2*)(r1 + wr);
        s.L2 = *(const float2*)(r2 + wl);
        s.M2 = *(const float2*)(r2 + w0);
        s.R2 = *(const float2*)(r2 + wr);
        size_t ob = (((size_t)bc * (2 * H) + (size_t)(2 * h)) * W2) + (size_t)(2 * w0);
        s.ya = *(const float4*)(y + ob);
        s.yb = *(const float4*)(y + ob + W2);
        return s;
    };

    auto act = [&](float v) { return fmaxf(fmaf(v, s_w1, s_b1), 0.f); };

    auto compute_store = [&](const Stage& s, int h) {
        const float m0 = (h >= DIA)    ? 1.f : 0.f;
        const float m2 = (h < H - DIA) ? 1.f : 0.f;
        float xo0 = act(s.M1.x);
        float xo1 = act(s.M1.y);
        float sum0 = mL * act(s.L1.x) + xo0 + mR * act(s.R1.x);
        float sum1 = mL * act(s.L1.y) + xo1 + mR * act(s.R1.y);
        sum0 += m0 * (mL * act(s.L0.x) + act(s.M0.x) + mR * act(s.R0.x));
        sum1 += m0 * (mL * act(s.L0.y) + act(s.M0.y) + mR * act(s.R0.y));
        sum0 += m2 * (mL * act(s.L2.x) + act(s.M2.x) + mR * act(s.R2.x));
        sum1 += m2 * (mL * act(s.L2.y) + act(s.M2.y) + mR * act(s.R2.y));
        float z0 = fmaf(sum0, s_w2, s_b2);
        float z1 = fmaf(sum1, s_w2, s_b2);
        float o0 = xo0 / (1.f + __expf(-z0));
        float o1 = xo1 / (1.f + __expf(-z1));
        size_t ob = (((size_t)bc * (2 * H) + (size_t)(2 * h)) * W2) + (size_t)(2 * w0);
        *(float4*)(out + ob)      = make_float4(s.ya.x + o0, s.ya.y + o0, s.ya.z + o1, s.ya.w + o1);
        *(float4*)(out + ob + W2) = make_float4(s.yb.x + o0, s.yb.y + o0, s.yb.z + o1, s.yb.w + o1);
    };

    // 2-deep pipeline, fully unrolled with named stages (no runtime-indexed
    // stage array -> no scratch). PIN(s_{k+1}) before compute(s_k) forces
    // next-stage loads issued & live while current stage computes.
    Stage s0 = load_stage(h0 + 0);
    Stage s1 = load_stage(h0 + 1);
    PIN(s1);
    compute_store(s0, h0 + 0);
    Stage s2 = load_stage(h0 + 2);
    PIN(s2);
    compute_store(s1, h0 + 1);
    Stage s3 = load_stage(h0 + 3);
    PIN(s3);
    compute_store(s2, h0 + 2);
    compute_store(s3, h0 + 3);
}

extern "C" void kernel_launch(void* const* d_in, const int* in_sizes, int n_in,
                              void* d_out, int out_size, void* d_ws, size_t ws_size,
                              hipStream_t stream) {
    const float* x  = (const float*)d_in[0];
    const float* y  = (const float*)d_in[1];
    const float* w1 = (const float*)d_in[2];
    const float* b1 = (const float*)d_in[3];
    const float* w2 = (const float*)d_in[4];
    const float* b2 = (const float*)d_in[5];
    float* out = (float*)d_out;

    int grid = 3072, block = 256;   // 4 rows per block
    fused_kernel<<<grid, block, 0, stream>>>(x, y, w1, b1, w2, b2, out);
}

// Round 7
// 207.152 us; speedup vs baseline: 1.0760x; 1.0760x over previous
//
#include <hip/hip_runtime.h>

// Fused: per-channel affine+relu -> dilated(2) 3x3 box-sum (zero pad) ->
// sigmoid gate -> multiply -> 2x nearest upsample -> add y.
//
// Mapping: 1 block = 1 input row (256 threads x 2 px); 1 thread -> 4x2 output
// block. Lanes stride 16 B on y/out: float4 accesses fully contiguous across
// the wave. R5: XCD-chunked block swizzle (kept; -24 MB HBM fetch).
//
// R6-R8: dur x occupancy == constant across every variant -> latency-bound,
// ~17K-cy wave lifetime ~= ~11-13 serialized VMEM latencies. Source-level
// batching pins all defeated by the compiler (VGPR counts 16/20/32 never
// consistent with a real batch).
// R9/R10: raw inline-asm global_load cluster -> container failed twice.
// Asm loads implicated; abandoned (unobservable failure mode).
//
// R11: reduce the NUMBER of serialized VMEM ops instead of batching them.
// Stage the three x-rows (h-2, h, h+2, clamped) in LDS: 3 coalesced float2
// global loads per thread (down from 9); the staged values ARE the M-taps
// (kept in registers); only the 6 L/R taps come back via ds_read_b64
// (~120 cy vs ~1.3K cy loaded VMEM latency -- 10x cheaper to serialize;
// 2-way bank aliasing on stride-8B is free). VMEM loads/thread: 11 -> 5.
// Zero inline asm: if the container dies again, it's conclusively infra.

#define DIA 2

__global__ __launch_bounds__(256) void fused_kernel(
    const float* __restrict__ x, const float* __restrict__ y,
    const float* __restrict__ w1v, const float* __restrict__ b1v,
    const float* __restrict__ w2v, const float* __restrict__ b2v,
    float* __restrict__ out)
{
    constexpr int C = 3, H = 512, W = 512, W2 = 1024;
    constexpr int NBLK = 12288, CHUNK = NBLK / 8;

    __shared__ float xs[3][W];           // rows h-2, h, h+2 (clamped): 6 KB

    // XCD-aware swizzle: consecutive hardware blockIdx round-robins across
    // 8 XCDs; remap so each XCD owns a contiguous chunk (12288 % 8 == 0).
    int g = blockIdx.x;
    int l = (g & 7) * CHUNK + (g >> 3);

    int h  = l & (H - 1);                // per-block -> scalar
    int bc = l >> 9;                     // 0..23 (b*C + c), scalar
    int c  = bc % C;
    int w0 = (int)threadIdx.x * 2;       // even, 0..510, lane-contiguous

    const float s_w1 = w1v[c], s_b1 = b1v[c];
    const float s_w2 = w2v[c], s_b2 = b2v[c];

    const float* __restrict__ xrow = x + ((size_t)bc * H + (size_t)h) * W;

    const bool ok0 = (h >= DIA), ok2 = (h < H - DIA);
    const float m0 = ok0 ? 1.f : 0.f;
    const float m2 = ok2 ? 1.f : 0.f;
    const float* r0 = ok0 ? (xrow - DIA * W) : xrow;   // clamped, in-bounds
    const float* r2 = ok2 ? (xrow + DIA * W) : xrow;

    // ---- stage: 3 coalesced float2 loads/thread; values stay in regs as
    // the M-taps while also being written to LDS for neighbors' L/R taps ----
    float2 M0 = *(const float2*)(r0 + w0);
    float2 M1 = *(const float2*)(xrow + w0);
    float2 M2 = *(const float2*)(r2 + w0);
    *(float2*)&xs[0][w0] = M0;
    *(float2*)&xs[1][w0] = M1;
    *(float2*)&xs[2][w0] = M2;
    __syncthreads();

    // y loads issued right after the barrier: their latency overlaps the
    // LDS tap reads + activation arithmetic below (consumed only at the end).
    size_t obase = (((size_t)bc * (2 * H) + (size_t)(2 * h)) * W2) + (size_t)(2 * w0);
    float4 ya = *(const float4*)(y + obase);
    float4 yb = *(const float4*)(y + obase + W2);

    const bool lok = (w0 > 0), rok = (w0 + 2 < W);
    const float mL = lok ? 1.f : 0.f;
    const float mR = rok ? 1.f : 0.f;
    const int wl = lok ? (w0 - 2) : w0;  // even -> 8B-aligned ds_read_b64
    const int wr = rok ? (w0 + 2) : w0;

    // ---- 6 L/R taps from LDS (2-way bank aliasing: free) ----
    float2 L0 = *(const float2*)&xs[0][wl];
    float2 R0 = *(const float2*)&xs[0][wr];
    float2 L1 = *(const float2*)&xs[1][wl];
    float2 R1 = *(const float2*)&xs[1][wr];
    float2 L2 = *(const float2*)&xs[2][wl];
    float2 R2 = *(const float2*)&xs[2][wr];

    // ---- compute ----
    auto act = [&](float v) { return fmaxf(fmaf(v, s_w1, s_b1), 0.f); };

    // center (= x_r): always valid
    float xo0 = act(M1.x);
    float xo1 = act(M1.y);

    float sum0 = mL * act(L1.x) + xo0 + mR * act(R1.x);
    float sum1 = mL * act(L1.y) + xo1 + mR * act(R1.y);
    sum0 += m0 * (mL * act(L0.x) + act(M0.x) + mR * act(R0.x));
    sum1 += m0 * (mL * act(L0.y) + act(M0.y) + mR * act(R0.y));
    sum0 += m2 * (mL * act(L2.x) + act(M2.x) + mR * act(R2.x));
    sum1 += m2 * (mL * act(L2.y) + act(M2.y) + mR * act(R2.y));

    float z0 = fmaf(sum0, s_w2, s_b2);
    float z1 = fmaf(sum1, s_w2, s_b2);
    float o0 = xo0 / (1.f + __expf(-z0));
    float o1 = xo1 / (1.f + __expf(-z1));

    // ---- 2x nearest upsample + add y (lane-contiguous float4 stores) ----
    *(float4*)(out + obase)      = make_float4(ya.x + o0, ya.y + o0, ya.z + o1, ya.w + o1);
    *(float4*)(out + obase + W2) = make_float4(yb.x + o0, yb.y + o0, yb.z + o1, yb.w + o1);
}

extern "C" void kernel_launch(void* const* d_in, const int* in_sizes, int n_in,
                              void* d_out, int out_size, void* d_ws, size_t ws_size,
                              hipStream_t stream) {
    const float* x  = (const float*)d_in[0];
    const float* y  = (const float*)d_in[1];
    const float* w1 = (const float*)d_in[2];
    const float* b1 = (const float*)d_in[3];
    const float* w2 = (const float*)d_in[4];
    const float* b2 = (const float*)d_in[5];
    float* out = (float*)d_out;

    int grid = 12288, block = 256;       // 1 block = 1 input row
    fused_kernel<<<grid, block, 0, stream>>>(x, y, w1, b1, w2, b2, out);
}

// Round 8
// 204.337 us; speedup vs baseline: 1.0908x; 1.0138x over previous
//
#include <hip/hip_runtime.h>

// Fused: per-channel affine+relu -> dilated(2) 3x3 box-sum (zero pad) ->
// sigmoid gate -> multiply -> 2x nearest upsample -> add y.
//
// R0-R11 ledger: dur locked at ~63-66 us across 11-load, 5-load+LDS,
// pipelined, and pinned variants; dur x occupancy == const; wave lifetime
// ~18K cy regardless of exposed-latency COUNT -> each exposure ~8K cy of
// QUEUEING delay. In-flight bytes (resident x per-wave) was conserved by
// every variant -- that's the invariant that has to break.
//
// R12: raise in-flight bytes with register-free DMA staging.
// __builtin_amdgcn_global_load_lds has no VGPR destination -> the register
// allocator (which serialized every register-load batch at 16 VGPRs across
// 3 attempts) has nothing to serialize. Each wave issues ~4 DMA calls
// (x segments + its two y-row slices) back-to-back -> ~4 KB in flight per
// wave, ~3x the machine-wide in-flight bytes. One vmcnt drain at the
// barrier. All taps then come from LDS: x float2 reads (2-way bank
// aliasing = free), y ds_read_b128 from the wave's own slice.
// Block = 1 row, 256 thr; XCD-chunked swizzle kept (-24 MB HBM fetch).
// LDS 14336 B/block -> not occupancy-limiting (wave cap 8 blocks/CU first).

#define DIA 2

typedef __attribute__((address_space(3))) void lds_void;
typedef const __attribute__((address_space(1))) void gmem_void;

__global__ __launch_bounds__(256) void fused_kernel(
    const float* __restrict__ x, const float* __restrict__ y,
    const float* __restrict__ w1v, const float* __restrict__ b1v,
    const float* __restrict__ w2v, const float* __restrict__ b2v,
    float* __restrict__ out)
{
    constexpr int C = 3, H = 512, W = 512, W2 = 1024;
    constexpr int NBLK = 12288, CHUNK = NBLK / 8;

    __shared__ float xs[3 * W];      // 6 KB: rows h-2, h, h+2 (clamped)
    __shared__ float ys[2 * W2];     // 8 KB: y output rows 2h, 2h+1

    // XCD-aware swizzle (12288 % 8 == 0 -> bijective).
    int g = blockIdx.x;
    int l = (g & 7) * CHUNK + (g >> 3);

    int h    = l & (H - 1);                 // scalar per block
    int bc   = l >> 9;                      // 0..23, scalar
    int c    = bc % C;
    int tid  = (int)threadIdx.x;
    int w0   = tid * 2;                     // even, 0..510
    int lane = tid & 63;
    int wv   = __builtin_amdgcn_readfirstlane(tid >> 6);   // wave id 0..3

    const float s_w1 = w1v[c], s_b1 = b1v[c];
    const float s_w2 = w2v[c], s_b2 = b2v[c];

    const float* xrow = x + ((size_t)bc * H + (size_t)h) * W;
    const bool ok0 = (h >= DIA), ok2 = (h < H - DIA);
    const float m0 = ok0 ? 1.f : 0.f;
    const float m2 = ok2 ? 1.f : 0.f;
    const float* xr0 = ok0 ? (xrow - DIA * W) : xrow;   // clamped, in-bounds
    const float* xr2 = ok2 ? (xrow + DIA * W) : xrow;

    size_t yrow = ((size_t)bc * (2 * H) + (size_t)(2 * h)) * W2;

    // ---- DMA staging: zero VGPR destinations, all calls in flight together.
    // x: 6 segments of 256 floats (seg s: row s>>1, half s&1).
    //    wave wv stages seg wv; waves 0,1 additionally stage segs 4,5.
    // y: wave wv stages its own 1KB slice of each of the 2 output rows.
    // LDS dest is wave-uniform base; HW adds lane*16. Global addr per-lane.
    auto rowptr = [&](int r) -> const float* {
        return r == 0 ? xr0 : (r == 1 ? xrow : xr2);
    };
    {
        int s = wv;                                    // segs 0..3
        const float* gp = rowptr(s >> 1) + (s & 1) * 256 + lane * 4;
        __builtin_amdgcn_global_load_lds((gmem_void*)gp,
                                         (lds_void*)(xs + s * 256), 16, 0, 0);
    }
    if (wv < 2) {
        int s = wv + 4;                                // segs 4,5 (row 2)
        const float* gp = rowptr(s >> 1) + (s & 1) * 256 + lane * 4;
        __builtin_amdgcn_global_load_lds((gmem_void*)gp,
                                         (lds_void*)(xs + s * 256), 16, 0, 0);
    }
    {
        const float* gpa = y + yrow + wv * 256 + lane * 4;
        const float* gpb = y + yrow + W2 + wv * 256 + lane * 4;
        __builtin_amdgcn_global_load_lds((gmem_void*)gpa,
                                         (lds_void*)(ys + wv * 256), 16, 0, 0);
        __builtin_amdgcn_global_load_lds((gmem_void*)gpb,
                                         (lds_void*)(ys + W2 + wv * 256), 16, 0, 0);
    }
    __syncthreads();   // single vmcnt(0) drain + barrier

    // ---- taps from LDS ----
    const bool lok = (w0 > 0), rok = (w0 + 2 < W);
    const float mL = lok ? 1.f : 0.f;
    const float mR = rok ? 1.f : 0.f;
    const int wl = lok ? (w0 - 2) : w0;   // even -> 8B-aligned
    const int wr = rok ? (w0 + 2) : w0;

    float2 L0 = *(const float2*)&xs[0 * W + wl];
    float2 M0 = *(const float2*)&xs[0 * W + w0];
    float2 R0 = *(const float2*)&xs[0 * W + wr];
    float2 L1 = *(const float2*)&xs[1 * W + wl];
    float2 M1 = *(const float2*)&xs[1 * W + w0];
    float2 R1 = *(const float2*)&xs[1 * W + wr];
    float2 L2 = *(const float2*)&xs[2 * W + wl];
    float2 M2 = *(const float2*)&xs[2 * W + w0];
    float2 R2 = *(const float2*)&xs[2 * W + wr];

    float4 ya = *(const float4*)&ys[2 * w0];        // cols 4t..4t+3, row 2h
    float4 yb = *(const float4*)&ys[W2 + 2 * w0];   // row 2h+1

    // ---- compute ----
    auto act = [&](float v) { return fmaxf(fmaf(v, s_w1, s_b1), 0.f); };

    float xo0 = act(M1.x);
    float xo1 = act(M1.y);

    float sum0 = mL * act(L1.x) + xo0 + mR * act(R1.x);
    float sum1 = mL * act(L1.y) + xo1 + mR * act(R1.y);
    sum0 += m0 * (mL * act(L0.x) + act(M0.x) + mR * act(R0.x));
    sum1 += m0 * (mL * act(L0.y) + act(M0.y) + mR * act(R0.y));
    sum0 += m2 * (mL * act(L2.x) + act(M2.x) + mR * act(R2.x));
    sum1 += m2 * (mL * act(L2.y) + act(M2.y) + mR * act(R2.y));

    float z0 = fmaf(sum0, s_w2, s_b2);
    float z1 = fmaf(sum1, s_w2, s_b2);
    float o0 = xo0 / (1.f + __expf(-z0));
    float o1 = xo1 / (1.f + __expf(-z1));

    // ---- 2x nearest upsample + add y (lane-contiguous float4 stores) ----
    size_t obase = yrow + (size_t)(2 * w0);
    *(float4*)(out + obase)      = make_float4(ya.x + o0, ya.y + o0, ya.z + o1, ya.w + o1);
    *(float4*)(out + obase + W2) = make_float4(yb.x + o0, yb.y + o0, yb.z + o1, yb.w + o1);
}

extern "C" void kernel_launch(void* const* d_in, const int* in_sizes, int n_in,
                              void* d_out, int out_size, void* d_ws, size_t ws_size,
                              hipStream_t stream) {
    const float* x  = (const float*)d_in[0];
    const float* y  = (const float*)d_in[1];
    const float* w1 = (const float*)d_in[2];
    const float* b1 = (const float*)d_in[3];
    const float* w2 = (const float*)d_in[4];
    const float* b2 = (const float*)d_in[5];
    float* out = (float*)d_out;

    int grid = 12288, block = 256;       // 1 block = 1 input row
    fused_kernel<<<grid, block, 0, stream>>>(x, y, w1, b1, w2, b2, out);
}